// Round 3
// baseline (349.437 us; speedup 1.0000x reference)
//
#include <hip/hip_runtime.h>
#include <cstddef>
#include <cstdint>

#define TILE 256

// Global accumulator slots (float, in ws[0..256)).
enum {
  // node kernel: 0..8
  A_EQ = 0, A_CNT_FREE, A_FREE, A_CNT_FFACE,
  A_SUPX, A_SUPY, A_SUPZ, A_CNT_SD, A_CNT_SR,
  // element kernel: 9..18 (MAXQ last: max-combined)
  A_SUM_E, A_SUM_A, A_SUM_I, A_SUM_L, A_LMK, A_LMPP,
  A_LN, A_LENDM, A_LENDV, A_MAXQ,
  A_COUNT
};

__device__ __forceinline__ float wave_sum(float v) {
#pragma unroll
  for (int off = 32; off > 0; off >>= 1) v += __shfl_down(v, off, 64);
  return v;
}
__device__ __forceinline__ float wave_max(float v) {
#pragma unroll
  for (int off = 32; off > 0; off >>= 1) v = fmaxf(v, __shfl_down(v, off, 64));
  return v;
}

// Block-level commit of NA per-thread partials into gacc[0..NA).
// maxSlot (if >=0) via atomicMax on float bits (values >= 0), else atomicAdd.
// Block must be 256 threads (4 waves). All threads must reach this.
template <int NA>
__device__ __forceinline__ void commit_acc(float* gacc, float (&l)[NA], int maxSlot) {
  __shared__ float s[4][NA];
  const int wid = threadIdx.x >> 6, lane = threadIdx.x & 63;
#pragma unroll
  for (int i = 0; i < NA; i++) {
    float r = (i == maxSlot) ? wave_max(l[i]) : wave_sum(l[i]);
    if (lane == 0) s[wid][i] = r;
  }
  __syncthreads();
  if ((int)threadIdx.x < NA) {
    const int i = threadIdx.x;
    if (i == maxSlot) {
      float m = fmaxf(fmaxf(s[0][i], s[1][i]), fmaxf(s[2][i], s[3][i]));
      atomicMax((unsigned int*)&gacc[i], __float_as_uint(m));
    } else {
      float v = (s[0][i] + s[1][i]) + (s[2][i] + s[3][i]);
      atomicAdd(&gacc[i], v);
    }
  }
}

// Coalesced stage of a contiguous float region (cnt floats, 16B-aligned base)
// into LDS. All 256 threads participate.
__device__ __forceinline__ void stage_floats(float* dst, const float* __restrict__ src,
                                             int cnt) {
  const int n4 = cnt >> 2;
  const float4* s4 = (const float4*)src;
  float4* d4 = (float4*)dst;
  for (int j = threadIdx.x; j < n4; j += 256) d4[j] = s4[j];
  for (int j = (n4 << 2) + threadIdx.x; j < cnt; j += 256) dst[j] = src[j];
}

// ---- Node kernel: L_eq, L_free, L_sup + planar ff scatter + dispc ----------
__global__ __launch_bounds__(256) void k_node(
    const float* __restrict__ pred, const float* __restrict__ F_ext,
    const float* __restrict__ bc_disp, const float* __restrict__ bc_rot,
    const float* __restrict__ face_mask,
    const int* __restrict__ f_eid, const int* __restrict__ f_isA,
    float* __restrict__ fAx, float* __restrict__ fAy, float* __restrict__ fAz,
    float* __restrict__ fBx, float* __restrict__ fBy, float* __restrict__ fBz,
    float2* __restrict__ dispc,
    float* __restrict__ gacc, int N, int E) {
  __shared__ float predT[TILE * 15];
  __shared__ float fextT[TILE * 3];
  float l[9];
#pragma unroll
  for (int i = 0; i < 9; i++) l[i] = 0.f;

  const int tileBase = blockIdx.x * TILE;
  const int cnt = (N - tileBase < TILE) ? (N - tileBase) : TILE;
  if (cnt > 0) {
    stage_floats(predT, pred + (size_t)tileBase * 15u, cnt * 15);
    stage_floats(fextT, F_ext + (size_t)tileBase * 3u, cnt * 3);
  }
  __syncthreads();

  const int t = threadIdx.x;
  if (t < cnt) {
    const int i = tileBase + t;
    const float* row = predT + t * 15;
    const float d0 = row[0], d1 = row[1], d2 = row[2];
    const float s0 = (row[3] + row[6]) + (row[9] + row[12]);
    const float s1 = (row[4] + row[7]) + (row[10] + row[13]);
    const float s2 = (row[5] + row[8]) + (row[11] + row[14]);
    const float r0 = s0 - fextT[t * 3];
    const float r1 = s1 - fextT[t * 3 + 1];
    const float r2 = s2 - fextT[t * 3 + 2];
    const float bd = bc_disp[i], br = bc_rot[i];
    if (bd < 0.5f) { l[0] += r0 * r0 + r1 * r1 + r2 * r2; l[1] += 1.f; }
    if (bd > 0.5f) { l[4] += d0 * d0; l[5] += d1 * d1; l[7] += 1.f; }
    if (br > 0.5f) { l[6] += d2 * d2; l[8] += 1.f; }
    const float4 fm = ((const float4*)face_mask)[i];
    const int4 fid = ((const int4*)f_eid)[i];
    const int4 fia = ((const int4*)f_isA)[i];
    const float* fmf = (const float*)&fm;
    const int* fidf = (const int*)&fid;
    const int* fiaf = (const int*)&fia;
#pragma unroll
    for (int f = 0; f < 4; f++) {
      const float x = row[3 + 3 * f], y = row[4 + 3 * f], z = row[5 + 3 * f];
      if (fmf[f] < 0.5f) {
        l[2] += x * x + y * y + z * z;
        l[3] += 1.f;
      } else {
        const int eid = fidf[f];
        const int isA = fiaf[f];
        if (eid >= 0 && eid < E) {
          if (isA == 1) {
            fAx[eid] = x; fAy[eid] = y; fAz[eid] = z;
          } else if (isA == 0) {
            fBx[eid] = x; fBy[eid] = y; fBz[eid] = z;
          }
        }
      }
    }
    dispc[i] = make_float2(d0, d1);
  }
  commit_acc<9>(gacc + A_EQ, l, -1);
}

// ---- Element kernel: ref sums, max|q|, L_Mk, L_Mpp, L_N, L_end ------------
__global__ __launch_bounds__(256) void k_elem(
    const int* __restrict__ conn, const float* __restrict__ dirs,
    const float* __restrict__ pE, const float* __restrict__ pA,
    const float* __restrict__ pI, const float* __restrict__ pL,
    const float* __restrict__ eload, const float* __restrict__ cw,
    const float* __restrict__ cMc,
    const float* __restrict__ fAx, const float* __restrict__ fAy,
    const float* __restrict__ fAz, const float* __restrict__ fBx,
    const float* __restrict__ fBy, const float* __restrict__ fBz,
    const float2* __restrict__ dispc, const float* __restrict__ pred,
    float* __restrict__ gacc, int N, int E) {
  __shared__ float eloT[TILE * 3];
  __shared__ float dirT[TILE * 3];
  __shared__ float cwT[TILE * 6];
  float l[10];  // SUM_E, SUM_A, SUM_I, SUM_L, LMK, LMPP, LN, LENDM, LENDV, MAXQ
#pragma unroll
  for (int i = 0; i < 10; i++) l[i] = 0.f;

  const int tileBase = blockIdx.x * TILE;
  const int cnt = (E - tileBase < TILE) ? (E - tileBase) : TILE;
  if (cnt > 0) {
    stage_floats(eloT, eload + (size_t)tileBase * 3u, cnt * 3);
    stage_floats(dirT, dirs + (size_t)tileBase * 3u, cnt * 3);
    stage_floats(cwT, cw + (size_t)tileBase * 6u, cnt * 6);
  }
  __syncthreads();

  const int t = threadIdx.x;
  if (t < cnt) {
    const int i = tileBase + t;
    const float e = pE[i], a = pA[i], ii = pI[i], L = pL[i];
    l[0] += e; l[1] += a; l[2] += ii; l[3] += L;
    const float invL = 1.0f / L, invL2 = invL * invL;
    const float q0 = eloT[t * 3], q1 = eloT[t * 3 + 1], q2 = eloT[t * 3 + 2];
    const float q = sqrtf(q0 * q0 + q1 * q1 + q2 * q2);
    l[9] = fmaxf(l[9], q);

    const float EI = e * ii;
    const float c2 = cwT[t * 6 + 2], c3 = cwT[t * 6 + 3];
    const float c4 = cwT[t * 6 + 4], c5 = cwT[t * 6 + 5];
    const float4 cm = ((const float4*)cMc)[i];
    const float m0 = cm.x, m1 = cm.y, m2 = cm.z, m3 = cm.w;
#pragma unroll
    for (int k = 0; k < 5; k++) {
      const float xi = 0.25f * (float)k;
      const float d2w = (2.f * c2 + xi * (6.f * c3 + xi * (12.f * c4 + xi * (20.f * c5)))) * invL2;
      const float M = m0 + xi * (m1 + xi * (m2 + xi * m3));
      const float tt = M - EI * d2w;
      l[4] += tt * tt;
      if (k >= 1 && k <= 3) {
        const float d2M = (2.f * m2 + 6.f * xi * m3) * invL2;
        const float u = d2M + q;
        l[5] += u * u;
      }
    }

    const int2 cn = ((const int2*)conn)[i];
    float dAx, dAy, dBx, dBy;
    if (dispc) {
      const float2 dA = dispc[cn.x];
      const float2 dB = dispc[cn.y];
      dAx = dA.x; dAy = dA.y; dBx = dB.x; dBy = dB.y;
    } else {
      dAx = pred[(size_t)cn.x * 15u]; dAy = pred[(size_t)cn.x * 15u + 1];
      dBx = pred[(size_t)cn.y * 15u]; dBy = pred[(size_t)cn.y * 15u + 1];
    }
    const float c = dirT[t * 3], s = dirT[t * 3 + 2];
    const float fax = fAx[i], fay = fAy[i], faz = fAz[i];
    const float fbx = fBx[i], fby = fBy[i], fbz = fBz[i];
    const float fA0 = fax * c + fay * s, fA1 = -fax * s + fay * c;
    const float fB0 = fbx * c + fby * s, fB1 = -fbx * s + fby * c;
    const float dA0 = dAx * c + dAy * s, dB0 = dBx * c + dBy * s;
    const float Nax = e * a * (dB0 - dA0) * invL;
    const float t0 = fA0 + Nax, t1 = fB0 - Nax;
    l[6] += t0 * t0 + t1 * t1;
    const float MA = m0, MB = (m0 + m1) + (m2 + m3);
    const float VA = m1 * invL, VB = (m1 + 2.f * m2 + 3.f * m3) * invL;
    const float e0 = faz + MA, e1 = fbz - MB;
    l[7] += e0 * e0 + e1 * e1;
    const float e2 = fA1 + VA, e3 = fB1 - VB;
    l[8] += e2 * e2 + e3 * e3;
  }
  commit_acc<10>(gacc + A_SUM_E, l, 9);
}

// ---------------- Finisher ----------------
__global__ void k_finish(const float* __restrict__ acc, float* __restrict__ out,
                         float fE) {
  if (threadIdx.x == 0 && blockIdx.x == 0) {
    const float E_ref = acc[A_SUM_E] / fE;
    const float A_ref = acc[A_SUM_A] / fE;
    const float I_ref = acc[A_SUM_I] / fE;
    const float L_ref = acc[A_SUM_L] / fE;
    float q0 = acc[A_MAXQ];
    if (q0 < 1e-10f) q0 = 1.0f;
    const float N_ref = fmaxf(E_ref * A_ref * 0.001f / L_ref, 1e-6f);
    const float M_ref = fmaxf(E_ref * I_ref * 0.001f / (L_ref * L_ref), 1e-6f);
    const float V_ref = fmaxf(M_ref / L_ref, 1e-6f);
    const float q_ref = fmaxf(q0, 1e-6f);
    const float F_ref = fmaxf(q0 * L_ref, 1e-6f);

    const float L_eq = acc[A_EQ] / (F_ref * F_ref) / fmaxf(acc[A_CNT_FREE], 1.f);
    const float L_free = acc[A_FREE] / (F_ref * F_ref) / fmaxf(acc[A_CNT_FFACE] * 3.f, 1.f);
    const float cd = fmaxf(acc[A_CNT_SD], 1.f), cr = fmaxf(acc[A_CNT_SR], 1.f);
    const float L_sup = acc[A_SUPX] / cd + acc[A_SUPY] / cd + acc[A_SUPZ] / cr;
    const float L_N = acc[A_LN] / (N_ref * N_ref) / fE;
    const float L_Mk = acc[A_LMK] / (M_ref * M_ref) / (fE * 5.f);
    const float L_Mpp = acc[A_LMPP] / (q_ref * q_ref) / (fE * 3.f);
    const float L_end = acc[A_LENDM] / (M_ref * M_ref) / fE +
                        acc[A_LENDV] / (V_ref * V_ref) / fE;
    out[0] = ((L_eq + L_free) + (L_sup + L_N)) + ((L_Mk + L_Mpp) + L_end);
  }
}

extern "C" void kernel_launch(void* const* d_in, const int* in_sizes, int n_in,
                              void* d_out, int out_size, void* d_ws, size_t ws_size,
                              hipStream_t stream) {
  const float* pred = (const float*)d_in[0];
  const float* F_ext = (const float*)d_in[1];
  const float* bc_disp = (const float*)d_in[2];
  const float* bc_rot = (const float*)d_in[3];
  const float* face_mask = (const float*)d_in[4];
  const float* dirs = (const float*)d_in[5];
  const float* pE = (const float*)d_in[6];
  const float* pA = (const float*)d_in[7];
  const float* pI = (const float*)d_in[8];
  const float* pL = (const float*)d_in[9];
  const float* eload = (const float*)d_in[10];
  const float* cw = (const float*)d_in[11];
  const float* cMc = (const float*)d_in[12];
  const int* conn = (const int*)d_in[13];
  const int* f_eid = (const int*)d_in[14];
  const int* f_isA = (const int*)d_in[15];

  const int N = in_sizes[1] / 3;  // F_ext is (N,3)
  const int E = in_sizes[6];      // prop_E is (E,)

  char* ws = (char*)d_ws;
  float* gacc = (float*)ws;
  size_t off = 256;
  float* fAx = (float*)(ws + off); off += (size_t)E * sizeof(float);
  float* fAy = (float*)(ws + off); off += (size_t)E * sizeof(float);
  float* fAz = (float*)(ws + off); off += (size_t)E * sizeof(float);
  float* fBx = (float*)(ws + off); off += (size_t)E * sizeof(float);
  float* fBy = (float*)(ws + off); off += (size_t)E * sizeof(float);
  float* fBz = (float*)(ws + off); off += (size_t)E * sizeof(float);
  float2* dispc = nullptr;
  if (ws_size >= off + (size_t)N * 2u * sizeof(float)) {
    dispc = (float2*)(ws + off); off += (size_t)N * 2u * sizeof(float);
  }

  hipMemsetAsync(gacc, 0, 256, stream);

  const int gridN = (N + TILE - 1) / TILE;
  const int gridE = (E + TILE - 1) / TILE;
  k_node<<<gridN, TILE, 0, stream>>>(pred, F_ext, bc_disp, bc_rot, face_mask,
                                     f_eid, f_isA, fAx, fAy, fAz, fBx, fBy, fBz,
                                     dispc, gacc, N, E);
  k_elem<<<gridE, TILE, 0, stream>>>(conn, dirs, pE, pA, pI, pL, eload, cw, cMc,
                                     fAx, fAy, fAz, fBx, fBy, fBz, dispc, pred,
                                     gacc, N, E);
  k_finish<<<1, 64, 0, stream>>>(gacc, (float*)d_out, (float)E);
}

// Round 4
// 144.068 us; speedup vs baseline: 2.4255x; 2.4255x over previous
//
#include <hip/hip_runtime.h>
#include <cstddef>
#include <cstdint>

#define TILE 256
#define MAXB 1024
#define PSLOTS 16  // floats per partial row (power of 2, >= slot count)

// Node partial slots (per-block row in partN):
//  0 EQ, 1 CNT_FREE, 2 FREE, 3 CNT_FFACE, 4 SUPX, 5 SUPY, 6 SUPZ, 7 CNT_SD, 8 CNT_SR
// Elem partial slots (per-block row in partE):
//  0 SUM_E, 1 SUM_A, 2 SUM_I, 3 SUM_L, 4 LMK, 5 LMPP, 6 LN, 7 LENDM, 8 LENDV, 9 MAXQ

__device__ __forceinline__ float wave_sum(float v) {
#pragma unroll
  for (int off = 32; off > 0; off >>= 1) v += __shfl_down(v, off, 64);
  return v;
}
__device__ __forceinline__ float wave_max(float v) {
#pragma unroll
  for (int off = 32; off > 0; off >>= 1) v = fmaxf(v, __shfl_down(v, off, 64));
  return v;
}

// Block-reduce NA per-thread partials and store to this block's 16-float row.
// Slots >= NA are written as 0 so the finisher can blind-reduce all 16.
// maxSlot (if >= 0) is combined with max (values >= 0). Block = 256 threads.
template <int NA>
__device__ __forceinline__ void commit_part(float* __restrict__ prow,
                                            float (&l)[NA], int maxSlot) {
  __shared__ float s[4][NA];
  const int wid = threadIdx.x >> 6, lane = threadIdx.x & 63;
#pragma unroll
  for (int i = 0; i < NA; i++) {
    float r = (i == maxSlot) ? wave_max(l[i]) : wave_sum(l[i]);
    if (lane == 0) s[wid][i] = r;
  }
  __syncthreads();
  if ((int)threadIdx.x < PSLOTS) {
    const int i = threadIdx.x;
    float v = 0.f;
    if (i < NA) {
      if (i == maxSlot)
        v = fmaxf(fmaxf(s[0][i], s[1][i]), fmaxf(s[2][i], s[3][i]));
      else
        v = (s[0][i] + s[1][i]) + (s[2][i] + s[3][i]);
    }
    prow[i] = v;
  }
}

// Coalesced stage of a contiguous float region into LDS (256 threads).
__device__ __forceinline__ void stage_floats(float* dst, const float* __restrict__ src,
                                             int cnt) {
  const int n4 = cnt >> 2;
  const float4* s4 = (const float4*)src;
  float4* d4 = (float4*)dst;
  for (int j = threadIdx.x; j < n4; j += 256) d4[j] = s4[j];
  for (int j = (n4 << 2) + threadIdx.x; j < cnt; j += 256) dst[j] = src[j];
}

// ---- Node kernel: L_eq, L_free, L_sup + planar ff scatter + dispc ----------
__global__ __launch_bounds__(256) void k_node(
    const float* __restrict__ pred, const float* __restrict__ F_ext,
    const float* __restrict__ bc_disp, const float* __restrict__ bc_rot,
    const float* __restrict__ face_mask,
    const int* __restrict__ f_eid, const int* __restrict__ f_isA,
    float* __restrict__ fAx, float* __restrict__ fAy, float* __restrict__ fAz,
    float* __restrict__ fBx, float* __restrict__ fBy, float* __restrict__ fBz,
    float2* __restrict__ dispc,
    float* __restrict__ partN, int N, int E) {
  __shared__ float predT[TILE * 15];
  __shared__ float fextT[TILE * 3];
  float l[9];
#pragma unroll
  for (int i = 0; i < 9; i++) l[i] = 0.f;

  const int tileStride = gridDim.x * TILE;
  for (int tileBase = blockIdx.x * TILE; tileBase < N; tileBase += tileStride) {
    const int cnt = (N - tileBase < TILE) ? (N - tileBase) : TILE;
    __syncthreads();  // protect LDS from previous iteration's readers
    stage_floats(predT, pred + (size_t)tileBase * 15u, cnt * 15);
    stage_floats(fextT, F_ext + (size_t)tileBase * 3u, cnt * 3);
    __syncthreads();

    const int t = threadIdx.x;
    if (t < cnt) {
      const int i = tileBase + t;
      const float* row = predT + t * 15;
      const float d0 = row[0], d1 = row[1], d2 = row[2];
      const float s0 = (row[3] + row[6]) + (row[9] + row[12]);
      const float s1 = (row[4] + row[7]) + (row[10] + row[13]);
      const float s2 = (row[5] + row[8]) + (row[11] + row[14]);
      const float r0 = s0 - fextT[t * 3];
      const float r1 = s1 - fextT[t * 3 + 1];
      const float r2 = s2 - fextT[t * 3 + 2];
      const float bd = bc_disp[i], br = bc_rot[i];
      if (bd < 0.5f) { l[0] += r0 * r0 + r1 * r1 + r2 * r2; l[1] += 1.f; }
      if (bd > 0.5f) { l[4] += d0 * d0; l[5] += d1 * d1; l[7] += 1.f; }
      if (br > 0.5f) { l[6] += d2 * d2; l[8] += 1.f; }
      const float4 fm = ((const float4*)face_mask)[i];
      const int4 fid = ((const int4*)f_eid)[i];
      const int4 fia = ((const int4*)f_isA)[i];
      const float* fmf = (const float*)&fm;
      const int* fidf = (const int*)&fid;
      const int* fiaf = (const int*)&fia;
#pragma unroll
      for (int f = 0; f < 4; f++) {
        const float x = row[3 + 3 * f], y = row[4 + 3 * f], z = row[5 + 3 * f];
        if (fmf[f] < 0.5f) {
          l[2] += x * x + y * y + z * z;
          l[3] += 1.f;
        } else {
          const int eid = fidf[f];
          const int isA = fiaf[f];
          if (eid >= 0 && eid < E) {
            if (isA == 1) {
              fAx[eid] = x; fAy[eid] = y; fAz[eid] = z;
            } else if (isA == 0) {
              fBx[eid] = x; fBy[eid] = y; fBz[eid] = z;
            }
          }
        }
      }
      dispc[i] = make_float2(d0, d1);
    }
  }
  __syncthreads();
  commit_part<9>(partN + (size_t)blockIdx.x * PSLOTS, l, -1);
}

// ---- Element kernel: ref sums, max|q|, L_Mk, L_Mpp, L_N, L_end ------------
__global__ __launch_bounds__(256) void k_elem(
    const int* __restrict__ conn, const float* __restrict__ dirs,
    const float* __restrict__ pE, const float* __restrict__ pA,
    const float* __restrict__ pI, const float* __restrict__ pL,
    const float* __restrict__ eload, const float* __restrict__ cw,
    const float* __restrict__ cMc,
    const float* __restrict__ fAx, const float* __restrict__ fAy,
    const float* __restrict__ fAz, const float* __restrict__ fBx,
    const float* __restrict__ fBy, const float* __restrict__ fBz,
    const float2* __restrict__ dispc, const float* __restrict__ pred,
    float* __restrict__ partE, int N, int E) {
  __shared__ float eloT[TILE * 3];
  __shared__ float dirT[TILE * 3];
  __shared__ float cwT[TILE * 6];
  float l[10];
#pragma unroll
  for (int i = 0; i < 10; i++) l[i] = 0.f;

  const int tileStride = gridDim.x * TILE;
  for (int tileBase = blockIdx.x * TILE; tileBase < E; tileBase += tileStride) {
    const int cnt = (E - tileBase < TILE) ? (E - tileBase) : TILE;
    __syncthreads();
    stage_floats(eloT, eload + (size_t)tileBase * 3u, cnt * 3);
    stage_floats(dirT, dirs + (size_t)tileBase * 3u, cnt * 3);
    stage_floats(cwT, cw + (size_t)tileBase * 6u, cnt * 6);
    __syncthreads();

    const int t = threadIdx.x;
    if (t < cnt) {
      const int i = tileBase + t;
      const float e = pE[i], a = pA[i], ii = pI[i], L = pL[i];
      l[0] += e; l[1] += a; l[2] += ii; l[3] += L;
      const float invL = 1.0f / L, invL2 = invL * invL;
      const float q0 = eloT[t * 3], q1 = eloT[t * 3 + 1], q2 = eloT[t * 3 + 2];
      const float q = sqrtf(q0 * q0 + q1 * q1 + q2 * q2);
      l[9] = fmaxf(l[9], q);

      const float EI = e * ii;
      const float c2 = cwT[t * 6 + 2], c3 = cwT[t * 6 + 3];
      const float c4 = cwT[t * 6 + 4], c5 = cwT[t * 6 + 5];
      const float4 cm = ((const float4*)cMc)[i];
      const float m0 = cm.x, m1 = cm.y, m2 = cm.z, m3 = cm.w;
#pragma unroll
      for (int k = 0; k < 5; k++) {
        const float xi = 0.25f * (float)k;
        const float d2w = (2.f * c2 + xi * (6.f * c3 + xi * (12.f * c4 + xi * (20.f * c5)))) * invL2;
        const float M = m0 + xi * (m1 + xi * (m2 + xi * m3));
        const float tt = M - EI * d2w;
        l[4] += tt * tt;
        if (k >= 1 && k <= 3) {
          const float d2M = (2.f * m2 + 6.f * xi * m3) * invL2;
          const float u = d2M + q;
          l[5] += u * u;
        }
      }

      const int2 cn = ((const int2*)conn)[i];
      float dAx, dAy, dBx, dBy;
      if (dispc) {
        const float2 dA = dispc[cn.x];
        const float2 dB = dispc[cn.y];
        dAx = dA.x; dAy = dA.y; dBx = dB.x; dBy = dB.y;
      } else {
        dAx = pred[(size_t)cn.x * 15u]; dAy = pred[(size_t)cn.x * 15u + 1];
        dBx = pred[(size_t)cn.y * 15u]; dBy = pred[(size_t)cn.y * 15u + 1];
      }
      const float c = dirT[t * 3], s = dirT[t * 3 + 2];
      const float fax = fAx[i], fay = fAy[i], faz = fAz[i];
      const float fbx = fBx[i], fby = fBy[i], fbz = fBz[i];
      const float fA0 = fax * c + fay * s, fA1 = -fax * s + fay * c;
      const float fB0 = fbx * c + fby * s, fB1 = -fbx * s + fby * c;
      const float dA0 = dAx * c + dAy * s, dB0 = dBx * c + dBy * s;
      const float Nax = e * a * (dB0 - dA0) * invL;
      const float t0 = fA0 + Nax, t1 = fB0 - Nax;
      l[6] += t0 * t0 + t1 * t1;
      const float MA = m0, MB = (m0 + m1) + (m2 + m3);
      const float VA = m1 * invL, VB = (m1 + 2.f * m2 + 3.f * m3) * invL;
      const float e0 = faz + MA, e1 = fbz - MB;
      l[7] += e0 * e0 + e1 * e1;
      const float e2 = fA1 + VA, e3 = fB1 - VB;
      l[8] += e2 * e2 + e3 * e3;
    }
  }
  __syncthreads();
  commit_part<10>(partE + (size_t)blockIdx.x * PSLOTS, l, 9);
}

// ---- Finisher: reduce partial rows + final formula (one 256-thread block) --
__global__ __launch_bounds__(256) void k_finish(
    const float* __restrict__ partN, int nBN,
    const float* __restrict__ partE, int nBE,
    float* __restrict__ out, float fE) {
  __shared__ float red[16][17];
  __shared__ float finN[16], finE[16];
  const int slot = threadIdx.x & 15;
  const int grp = threadIdx.x >> 4;  // 0..15

  float acc = 0.f;
  for (int b = grp; b < nBN; b += 16) acc += partN[(size_t)b * PSLOTS + slot];
  red[grp][slot] = acc;
  __syncthreads();
  if ((int)threadIdx.x < 16) {
    float s = 0.f;
#pragma unroll
    for (int g = 0; g < 16; g++) s += red[g][threadIdx.x];
    finN[threadIdx.x] = s;
  }
  __syncthreads();

  float accS = 0.f, accM = 0.f;
  for (int b = grp; b < nBE; b += 16) {
    const float v = partE[(size_t)b * PSLOTS + slot];
    accS += v;
    accM = fmaxf(accM, v);
  }
  red[grp][slot] = (slot == 9) ? accM : accS;
  __syncthreads();
  if ((int)threadIdx.x < 16) {
    float s = 0.f;
    if (threadIdx.x == 9) {
#pragma unroll
      for (int g = 0; g < 16; g++) s = fmaxf(s, red[g][9]);
    } else {
#pragma unroll
      for (int g = 0; g < 16; g++) s += red[g][threadIdx.x];
    }
    finE[threadIdx.x] = s;
  }
  __syncthreads();

  if (threadIdx.x == 0) {
    const float E_ref = finE[0] / fE;
    const float A_ref = finE[1] / fE;
    const float I_ref = finE[2] / fE;
    const float L_ref = finE[3] / fE;
    float q0 = finE[9];
    if (q0 < 1e-10f) q0 = 1.0f;
    const float N_ref = fmaxf(E_ref * A_ref * 0.001f / L_ref, 1e-6f);
    const float M_ref = fmaxf(E_ref * I_ref * 0.001f / (L_ref * L_ref), 1e-6f);
    const float V_ref = fmaxf(M_ref / L_ref, 1e-6f);
    const float q_ref = fmaxf(q0, 1e-6f);
    const float F_ref = fmaxf(q0 * L_ref, 1e-6f);

    const float L_eq = finN[0] / (F_ref * F_ref) / fmaxf(finN[1], 1.f);
    const float L_free = finN[2] / (F_ref * F_ref) / fmaxf(finN[3] * 3.f, 1.f);
    const float cd = fmaxf(finN[7], 1.f), cr = fmaxf(finN[8], 1.f);
    const float L_sup = finN[4] / cd + finN[5] / cd + finN[6] / cr;
    const float L_N = finE[6] / (N_ref * N_ref) / fE;
    const float L_Mk = finE[4] / (M_ref * M_ref) / (fE * 5.f);
    const float L_Mpp = finE[5] / (q_ref * q_ref) / (fE * 3.f);
    const float L_end = finE[7] / (M_ref * M_ref) / fE +
                        finE[8] / (V_ref * V_ref) / fE;
    out[0] = ((L_eq + L_free) + (L_sup + L_N)) + ((L_Mk + L_Mpp) + L_end);
  }
}

extern "C" void kernel_launch(void* const* d_in, const int* in_sizes, int n_in,
                              void* d_out, int out_size, void* d_ws, size_t ws_size,
                              hipStream_t stream) {
  const float* pred = (const float*)d_in[0];
  const float* F_ext = (const float*)d_in[1];
  const float* bc_disp = (const float*)d_in[2];
  const float* bc_rot = (const float*)d_in[3];
  const float* face_mask = (const float*)d_in[4];
  const float* dirs = (const float*)d_in[5];
  const float* pE = (const float*)d_in[6];
  const float* pA = (const float*)d_in[7];
  const float* pI = (const float*)d_in[8];
  const float* pL = (const float*)d_in[9];
  const float* eload = (const float*)d_in[10];
  const float* cw = (const float*)d_in[11];
  const float* cMc = (const float*)d_in[12];
  const int* conn = (const int*)d_in[13];
  const int* f_eid = (const int*)d_in[14];
  const int* f_isA = (const int*)d_in[15];

  const int N = in_sizes[1] / 3;  // F_ext is (N,3)
  const int E = in_sizes[6];      // prop_E is (E,)

  char* ws = (char*)d_ws;
  size_t off = 0;
  float* partN = (float*)(ws + off); off += (size_t)MAXB * PSLOTS * sizeof(float);
  float* partE = (float*)(ws + off); off += (size_t)MAXB * PSLOTS * sizeof(float);
  float* fAx = (float*)(ws + off); off += (size_t)E * sizeof(float);
  float* fAy = (float*)(ws + off); off += (size_t)E * sizeof(float);
  float* fAz = (float*)(ws + off); off += (size_t)E * sizeof(float);
  float* fBx = (float*)(ws + off); off += (size_t)E * sizeof(float);
  float* fBy = (float*)(ws + off); off += (size_t)E * sizeof(float);
  float* fBz = (float*)(ws + off); off += (size_t)E * sizeof(float);
  float2* dispc = nullptr;
  if (ws_size >= off + (size_t)N * 2u * sizeof(float)) {
    dispc = (float2*)(ws + off); off += (size_t)N * 2u * sizeof(float);
  }

  int gridN = (N + TILE - 1) / TILE; if (gridN > MAXB) gridN = MAXB;
  int gridE = (E + TILE - 1) / TILE; if (gridE > MAXB) gridE = MAXB;

  k_node<<<gridN, TILE, 0, stream>>>(pred, F_ext, bc_disp, bc_rot, face_mask,
                                     f_eid, f_isA, fAx, fAy, fAz, fBx, fBy, fBz,
                                     dispc, partN, N, E);
  k_elem<<<gridE, TILE, 0, stream>>>(conn, dirs, pE, pA, pI, pL, eload, cw, cMc,
                                     fAx, fAy, fAz, fBx, fBy, fBz, dispc, pred,
                                     partE, N, E);
  k_finish<<<1, 256, 0, stream>>>(partN, gridN, partE, gridE,
                                  (float*)d_out, (float)E);
}